// Round 6
// baseline (234.978 us; speedup 1.0000x reference)
//
#include <hip/hip_runtime.h>

// ProposalLayer for Faster R-CNN RPN on MI355X — single fused kernel, v2.
// B=4, H=64, W=96, A=9 anchors, N=55296 anchors/image.
// TEST cfg: pre=6000, post=300, thresh=0.7, min_size=16.
//
// Phases (3 device-wide barriers, 216 co-resident blocks of 1024 threads):
//   decode(+hist) -> B0 -> pivot(redundant per block)+compact -> B1 ->
//   rank -> B2 -> scatter+NMS (blocks 0-3) | hist-zero (blocks 4+)
// Co-residency: 216 blocks <= 256 CUs at 1 block/CU -> spin barrier safe.
// Barrier: increments are RMW, polls are agent-scope LOADS (read-shared, no
// cacheline ownership ping-pong); each barrier slot padded to 128B.

#define NB 4
#define AH 64
#define AW 96
#define NA 9
#define NPOS (AH*AW)        // 6144
#define NPC (NPOS*NA)       // 55296
#define CAP 16384           // candidate buffer per image
#define PREMAX 12000        // max 'pre' (TRAIN)
#define POSTMAX 2048        // max 'post' (TRAIN)
#define HBITS 15
#define HSZ (1<<HBITS)      // 32768 bins
#define HSH (32-HBITS)      // key >> 17
#define NTHR 1024
#define UPB (NPOS/NTHR)     // 6 position-chunks per (b,a)
#define NBLK (NB*NA*UPB)    // 216 blocks == decode/compact units

// anchors from _generate_anchors(16, (0.5,1,2), (8,16,32)) — verified vs numpy
__constant__ float c_anchors[NA][4] = {
  { -84.f,  -40.f,  99.f,  55.f},
  {-176.f,  -88.f, 191.f, 103.f},
  {-360.f, -184.f, 375.f, 199.f},
  { -56.f,  -56.f,  71.f,  71.f},
  {-120.f, -120.f, 135.f, 135.f},
  {-248.f, -248.f, 263.f, 263.f},
  { -36.f,  -80.f,  51.f,  95.f},
  { -80.f, -168.f,  95.f, 183.f},
  {-168.f, -344.f, 183.f, 359.f},
};

// static scratch. Call-to-call invariants (first call sees .bss zeros):
// g_h15 zeroed by idle blocks in phase 5; g_cnt zeroed by block 0 pre-B0;
// g_rank zeroed by the NMS scatter; g_bar reset by the last finalize arriver.
__device__ float4             g_boxes[NB][NPC];   // storage order i2 = a*NPOS+pos
__device__ unsigned int       g_h15[NB][HSZ];
__device__ int                g_cnt[NB];
__device__ unsigned long long g_cand[NB][CAP];    // key<<32 | ~iref (sort key)
__device__ int                g_cidx[NB][CAP];    // storage index i2
__device__ int                g_rank[NB][CAP];
__device__ float4             g_sbox[NB][PREMAX];
__device__ unsigned int       g_bar[8*32];        // one slot per 128B

// device-wide barrier: RMW arrive, LOAD-poll (no ownership ping-pong).
__device__ __forceinline__ void gbar(int k) {
  __syncthreads();
  if (threadIdx.x == 0) {
    __threadfence();
    __hip_atomic_fetch_add(&g_bar[k*32], 1u, __ATOMIC_ACQ_REL, __HIP_MEMORY_SCOPE_AGENT);
    while (__hip_atomic_load(&g_bar[k*32], __ATOMIC_ACQUIRE, __HIP_MEMORY_SCOPE_AGENT)
           < (unsigned)NBLK)
      __builtin_amdgcn_s_sleep(2);
    __threadfence();
  }
  __syncthreads();
}

// exact-equivalent "iou > 0.7f" without a division on the hot path:
// |inter - 0.7*denom| > 4e-6*denom decides the sign safely; the ~never-taken
// borderline falls back to the exact IEEE division the reference performs.
__device__ __forceinline__ bool iou_gt(float4 a, float areaA, float4 q, float areaQ) {
#pragma clang fp contract(off)
  float iw = fminf(a.z, q.z) - fmaxf(a.x, q.x) + 1.0f; iw = fmaxf(iw, 0.0f);
  float ih = fminf(a.w, q.w) - fmaxf(a.y, q.y) + 1.0f; ih = fmaxf(ih, 0.0f);
  float inter = iw * ih;
  float denom = areaA + areaQ - inter;
  float d = inter - 0.7f * denom;
  if (__builtin_expect(fabsf(d) <= 4e-6f * denom, 0))
    return (inter / denom) > 0.7f;
  return d > 0.0f;
}

__global__ void __launch_bounds__(NTHR)
k_all(const float* __restrict__ cls, const float* __restrict__ dlt,
      const float* __restrict__ ish, const int* __restrict__ train,
      float* __restrict__ out, int post) {
#pragma clang fp contract(off)
  const int tid = threadIdx.x;
  const int bid = blockIdx.x;
  const int pre = train[0] ? 12000 : 6000;

  // unit mapping (same for decode and compact)
  const int b   = bid / (NA*UPB);
  const int r   = bid % (NA*UPB);
  const int a   = r / UPB;
  const int pos = (r % UPB) * NTHR + tid;
  const int i2  = a * NPOS + pos;

  __shared__ float4 kbox[POSTMAX];
  __shared__ float  kar [POSTMAX];
  __shared__ float4 cbox[64];
  __shared__ float  car [64];
  __shared__ unsigned long long conf16[16][64];
  __shared__ unsigned long long sup16[16];
  __shared__ int s_nk;
  __shared__ unsigned int csum[NTHR];
  __shared__ unsigned int c32[32];
  __shared__ unsigned int c32s[33];
  __shared__ int sBest;
  __shared__ unsigned long long tl[256];

  // ================= phase 1: decode (one unit per block) =================
  if (bid == 0 && tid < NB) g_cnt[tid] = 0;   // visible after B0

  unsigned int key;   // stays in a register for compact
  {
    int wx = pos % AW;
    int hy = pos / AW;

    float score = cls[(b * (2*NA) + NA + a) * NPOS + pos];
    const float* dp = dlt + (b * (4*NA) + a*4) * NPOS + pos;
    float d0 = dp[0];
    float d1 = dp[NPOS];
    float d2 = dp[2*NPOS];
    float d3 = dp[3*NPOS];

    float shx = (float)(wx * 16);
    float shy = (float)(hy * 16);
    float ax1 = c_anchors[a][0] + shx;
    float ay1 = c_anchors[a][1] + shy;
    float ax2 = c_anchors[a][2] + shx;
    float ay2 = c_anchors[a][3] + shy;

    float aw_ = ax2 - ax1 + 1.0f;
    float ah_ = ay2 - ay1 + 1.0f;
    float acx = ax1 + 0.5f * aw_;
    float acy = ay1 + 0.5f * ah_;

    float pcx = d0 * aw_ + acx;
    float pcy = d1 * ah_ + acy;
    float pw  = expf(d2) * aw_;
    float ph  = expf(d3) * ah_;

    float x1 = pcx - 0.5f * pw;
    float y1 = pcy - 0.5f * ph;
    float x2 = pcx + 0.5f * pw;
    float y2 = pcy + 0.5f * ph;

    float imh = ish[b*2 + 0];
    float imw = ish[b*2 + 1];
    x1 = fminf(fmaxf(x1, 0.0f), imw - 1.0f);
    x2 = fminf(fmaxf(x2, 0.0f), imw - 1.0f);
    y1 = fminf(fmaxf(y1, 0.0f), imh - 1.0f);
    y2 = fminf(fmaxf(y2, 0.0f), imh - 1.0f);

    bool valid = ((x2 - x1 + 1.0f) >= 16.0f) && ((y2 - y1 + 1.0f) >= 16.0f);

    g_boxes[b][i2] = make_float4(x1, y1, x2, y2);

    key = 0u;
    if (valid) {
      unsigned int ub = __float_as_uint(score);
      key = (ub >> 31) ? ~ub : (ub | 0x80000000u);  // monotonic flip
    }
    atomicAdd(&g_h15[b][key >> HSH], 1u);           // key==0 -> bucket 0
  }
  gbar(0);

  // ========== phase 2: pivot (redundant per block) + compact ==========
  {
    const int CH = HSZ / NTHR;   // 32 bins/thread
    unsigned int hb[CH];
    const uint4* hp = (const uint4*)&g_h15[b][tid * CH];
#pragma unroll
    for (int q = 0; q < CH/4; ++q) {
      uint4 v = hp[q];
      hb[4*q+0] = v.x; hb[4*q+1] = v.y; hb[4*q+2] = v.z; hb[4*q+3] = v.w;
    }
    unsigned int s = 0;
#pragma unroll
    for (int q = 0; q < CH; ++q) s += hb[q];
    csum[tid] = s;
    if (tid == 0) sBest = 0;
    __syncthreads();
    if (tid < 32) {
      unsigned int ss = 0;
      for (int q = 0; q < 32; ++q) ss += csum[tid*32 + q];
      c32[tid] = ss;
    }
    __syncthreads();
    if (tid == 0) {
      unsigned int run = 0; c32s[32] = 0;
      for (int c = 31; c >= 0; --c) { run += c32[c]; c32s[c] = run; }
    }
    __syncthreads();
    unsigned int run = c32s[(tid >> 5) + 1];
    for (int t2 = (tid | 31); t2 > tid; --t2) run += csum[t2];
    int loc = 0;
#pragma unroll
    for (int q = CH-1; q >= 0; --q) {
      run += hb[q];
      if (!loc && run >= (unsigned)pre) {
        int T = tid * CH + q;
        if (T >= 1) loc = T;
      }
    }
    if (loc) atomicMax(&sBest, loc);
    __syncthreads();
    unsigned int pivot = sBest ? ((unsigned int)sBest << HSH) : 1u;

    if (key >= pivot) {              // pivot >= 1, key==0 auto-excluded
      int p = atomicAdd(&g_cnt[b], 1);
      if (p < CAP) {
        unsigned int iref = (unsigned int)(pos * NA + a);   // reference order
        g_cand[b][p] = ((unsigned long long)key << 32) |
                       (unsigned long long)(0xFFFFFFFFu - iref);
        g_cidx[b][p] = i2;
      }
    }
  }
  gbar(1);

  // ================= phase 3: exact rank =================
  for (int bb = 0; bb < NB; ++bb) {
    int C = g_cnt[bb]; if (C > CAP) C = CAP;
    int ntJ = (C + NTHR-1) >> 10;
    int ntK = (C + 255) >> 8;
    int jobs = ntJ * ntK;
    for (int t = bid; t < jobs; t += NBLK) {
      int jt = t / ntK, kt = t - jt * ntK;
      if (tid < 256) {
        int k = kt * 256 + tid;
        tl[tid] = (k < C) ? g_cand[bb][k] : 0ull;  // 0 pad: never > cj
      }
      __syncthreads();
      int j = jt * NTHR + tid;
      unsigned long long cj = (j < C) ? g_cand[bb][j] : ~0ull;
      int rk = 0;
#pragma unroll 8
      for (int q = 0; q < 256; ++q) rk += (int)(tl[q] > cj);
      if (j < C && rk) atomicAdd(&g_rank[bb][j], rk);
      __syncthreads();
    }
  }
  gbar(2);

  // ========== phase 4: scatter + NMS (blocks 0-3) | hist zero (rest) ==========
  if (bid < NB) {
    int lane = tid & 63;
    int wid  = tid >> 6;   // 16 waves
    int Cb = g_cnt[bid]; if (Cb > CAP) Cb = CAP;
    int Kb = min(pre, Cb);

    // scatter into sorted order; reset g_rank for the next call
    for (int j = tid; j < Cb; j += NTHR) {
      int rkk = g_rank[bid][j];
      g_rank[bid][j] = 0;
      if (rkk < pre) g_sbox[bid][rkk] = g_boxes[bid][g_cidx[bid][j]];
    }
    if (tid == 0) s_nk = 0;
    __syncthreads();

    // stage chunk 0
    if (wid == 15) {
      float4 bx0 = (lane < Kb) ? g_sbox[bid][lane] : make_float4(0.f,0.f,-1.f,-1.f);
      cbox[lane] = bx0;
      car[lane]  = (bx0.z - bx0.x + 1.0f) * (bx0.w - bx0.y + 1.0f);
    }
    __syncthreads();

    int nk = 0;
    unsigned long long laneBitsBelow = (lane == 0) ? 0ull : (~0ull >> (64 - lane));

    for (int base = 0; base < Kb; base += 64) {
      float4 bx  = cbox[lane];
      float area = car[lane];
      bool active = (base + lane < Kb);

      // wave15: prefetch next chunk into regs (hidden under supp loop)
      float4 nxt = make_float4(0.f, 0.f, -1.f, -1.f);
      if (wid == 15) {
        int c2 = base + 64 + lane;
        if (c2 < Kb) nxt = g_sbox[bid][c2];
      }

      // suppression vs kept boxes: stride-16, unrolled x4
      int supp = active ? 0 : 1;
      {
        int t = wid;
        for (; t + 48 < nk; t += 64) {
          supp |= (int)iou_gt(bx, area, kbox[t],    kar[t]);
          supp |= (int)iou_gt(bx, area, kbox[t+16], kar[t+16]);
          supp |= (int)iou_gt(bx, area, kbox[t+32], kar[t+32]);
          supp |= (int)iou_gt(bx, area, kbox[t+48], kar[t+48]);
        }
        for (; t < nk; t += 16) supp |= (int)iou_gt(bx, area, kbox[t], kar[t]);
      }
      unsigned long long sb = __ballot(supp);
      if (lane == 0) sup16[wid] = sb;

      // intra-chunk conflict bits: wave w covers j in [w*4, w*4+4)
      {
        unsigned long long confp = 0ull;
#pragma unroll
        for (int q = 0; q < 4; ++q) {
          int j = (wid << 2) + q;
          if (iou_gt(bx, area, cbox[j], car[j])) confp |= (1ull << j);
        }
        conf16[wid][lane] = confp;
      }
      __syncthreads();   // sup16/conf16 ready; cbox free to overwrite

      if (wid == 0) {
        unsigned long long conf = 0ull;
#pragma unroll
        for (int w = 0; w < 16; ++w) conf |= conf16[w][lane];
        conf &= laneBitsBelow;
        unsigned long long supAll = 0ull;
#pragma unroll
        for (int w = 0; w < 16; ++w) supAll |= sup16[w];
        unsigned long long pending = ~supAll;
        unsigned long long keptmask = 0ull;
        while (pending) {
          int i = __ffsll(pending) - 1;
          keptmask |= (1ull << i);
          unsigned long long confb = __ballot((int)((conf >> i) & 1ull));
          pending &= ~confb;
          pending &= ~(1ull << i);
        }
        int myPos = nk + __popcll(keptmask & laneBitsBelow);
        if (((keptmask >> lane) & 1ull) && myPos < post) {
          kbox[myPos] = bx;
          kar [myPos] = area;
          float* o = out + ((size_t)bid * post + myPos) * 5;
          o[0] = (float)bid; o[1] = bx.x; o[2] = bx.y; o[3] = bx.z; o[4] = bx.w;
        }
        if (lane == 0) s_nk = nk + __popcll(keptmask);
      } else if (wid == 15) {
        cbox[lane] = nxt;
        car[lane]  = (nxt.z - nxt.x + 1.0f) * (nxt.w - nxt.y + 1.0f);
      }
      __syncthreads();   // s_nk, kbox, new cbox ready
      nk = s_nk;
      if (nk >= post) break;
    }

    nk = min(nk, post);
    for (int rr = nk + tid; rr < post; rr += NTHR) {
      float* o = out + ((size_t)bid * post + rr) * 5;
      o[0] = (float)bid; o[1] = 0.0f; o[2] = 0.0f; o[3] = 0.0f; o[4] = 0.0f;
    }
  } else {
    // idle blocks zero the histogram for the next call
    int idx = (bid - NB) * NTHR + tid;
    if (idx < NB*HSZ/4) {
      uint4* hz = (uint4*)g_h15;
      hz[idx] = make_uint4(0u, 0u, 0u, 0u);
    }
  }

  // ================= finalize: reset barrier counters =================
  __syncthreads();
  if (tid == 0) {
    __threadfence();
    unsigned int p = __hip_atomic_fetch_add(&g_bar[7*32], 1u,
                        __ATOMIC_ACQ_REL, __HIP_MEMORY_SCOPE_AGENT);
    if (p == (unsigned)(NBLK - 1)) {      // true last arriver
      for (int k = 0; k < 8; ++k)
        __hip_atomic_store(&g_bar[k*32], 0u, __ATOMIC_RELEASE, __HIP_MEMORY_SCOPE_AGENT);
    }
  }
}

extern "C" void kernel_launch(void* const* d_in, const int* in_sizes, int n_in,
                              void* d_out, int out_size, void* d_ws, size_t ws_size,
                              hipStream_t stream) {
  (void)in_sizes; (void)n_in; (void)d_ws; (void)ws_size;
  const float* cls   = (const float*)d_in[0];
  const float* dlt   = (const float*)d_in[1];
  const float* ish   = (const float*)d_in[2];
  const int*   train = (const int*)d_in[3];
  float* out = (float*)d_out;

  int post = out_size / (NB * 5);  // 300 for TEST, 2000 for TRAIN

  k_all<<<NBLK, NTHR, 0, stream>>>(cls, dlt, ish, train, out, post);
}

// Round 7
// 172.226 us; speedup vs baseline: 1.3644x; 1.3644x over previous
//
#include <hip/hip_runtime.h>

// ProposalLayer for Faster R-CNN RPN on MI355X — 4 kernels, NO device barriers.
// B=4, H=64, W=96, A=9 anchors, N=55296 anchors/image.
// TEST cfg: pre=6000, post=300, thresh=0.7, min_size=16.
//
// k1_decode: decode boxes/keys + 15-bit score histogram
// k2_pivcmp: per-block redundant pivot from histogram + candidate compact
// k3_rank:   exact rank (desc key, asc index) via 256x256 LDS tiles
// k4_nms:    blocks 0-3: scatter-to-sorted + 16-wave batched greedy NMS
//            blocks 4-31: zero histogram for next call
// Cross-call invariants (first call sees .bss zeros): g_h15 zeroed by k4
// idle blocks; g_cnt read-then-zeroed by its consumer block in k4; g_rank
// read-then-zeroed by k4's scatter.

#define NB 4
#define AH 64
#define AW 96
#define NA 9
#define NPOS (AH*AW)        // 6144
#define NPC (NPOS*NA)       // 55296
#define CAP 16384           // candidate buffer per image
#define PREMAX 12000        // max 'pre' (TRAIN)
#define POSTMAX 2048        // max 'post' (TRAIN)
#define HBITS 15
#define HSZ (1<<HBITS)      // 32768 bins
#define HSH (32-HBITS)      // key >> 17

// anchors from _generate_anchors(16, (0.5,1,2), (8,16,32)) — verified vs numpy
__constant__ float c_anchors[NA][4] = {
  { -84.f,  -40.f,  99.f,  55.f},
  {-176.f,  -88.f, 191.f, 103.f},
  {-360.f, -184.f, 375.f, 199.f},
  { -56.f,  -56.f,  71.f,  71.f},
  {-120.f, -120.f, 135.f, 135.f},
  {-248.f, -248.f, 263.f, 263.f},
  { -36.f,  -80.f,  51.f,  95.f},
  { -80.f, -168.f,  95.f, 183.f},
  {-168.f, -344.f, 183.f, 359.f},
};

__device__ unsigned int       g_keys[NB][NPC];    // storage order i2 = a*NPOS+pos
__device__ float4             g_boxes[NB][NPC];
__device__ unsigned int       g_h15[NB][HSZ];
__device__ int                g_cnt[NB];
__device__ unsigned long long g_cand[NB][CAP];    // key<<32 | ~iref (sort key)
__device__ int                g_cidx[NB][CAP];    // storage index i2
__device__ int                g_rank[NB][CAP];
__device__ float4             g_sbox[NB][PREMAX];

// exact-equivalent "iou > 0.7f" without a division on the hot path:
// |inter - 0.7*denom| > 4e-6*denom decides the sign safely; the ~never-taken
// borderline falls back to the exact IEEE division the reference performs.
__device__ __forceinline__ bool iou_gt(float4 a, float areaA, float4 q, float areaQ) {
#pragma clang fp contract(off)
  float iw = fminf(a.z, q.z) - fmaxf(a.x, q.x) + 1.0f; iw = fmaxf(iw, 0.0f);
  float ih = fminf(a.w, q.w) - fmaxf(a.y, q.y) + 1.0f; ih = fmaxf(ih, 0.0f);
  float inter = iw * ih;
  float denom = areaA + areaQ - inter;
  float d = inter - 0.7f * denom;
  if (__builtin_expect(fabsf(d) <= 4e-6f * denom, 0))
    return (inter / denom) > 0.7f;
  return d > 0.0f;
}

// ================= k1: decode =================
// grid: NB*NA*(NPOS/256) = 864 blocks x 256
__global__ void __launch_bounds__(256)
k1_decode(const float* __restrict__ cls, const float* __restrict__ dlt,
          const float* __restrict__ ish) {
#pragma clang fp contract(off)
  const int UPB = NPOS/256;                  // 24
  int bid = blockIdx.x;
  int b   = bid / (NA*UPB);
  int r   = bid % (NA*UPB);
  int a   = r / UPB;
  int pos = (r % UPB) * 256 + threadIdx.x;
  int i2  = a * NPOS + pos;

  int wx = pos % AW;
  int hy = pos / AW;

  float score = cls[(b * (2*NA) + NA + a) * NPOS + pos];
  const float* dp = dlt + (b * (4*NA) + a*4) * NPOS + pos;
  float d0 = dp[0];
  float d1 = dp[NPOS];
  float d2 = dp[2*NPOS];
  float d3 = dp[3*NPOS];

  float shx = (float)(wx * 16);
  float shy = (float)(hy * 16);
  float ax1 = c_anchors[a][0] + shx;
  float ay1 = c_anchors[a][1] + shy;
  float ax2 = c_anchors[a][2] + shx;
  float ay2 = c_anchors[a][3] + shy;

  float aw_ = ax2 - ax1 + 1.0f;
  float ah_ = ay2 - ay1 + 1.0f;
  float acx = ax1 + 0.5f * aw_;
  float acy = ay1 + 0.5f * ah_;

  float pcx = d0 * aw_ + acx;
  float pcy = d1 * ah_ + acy;
  float pw  = expf(d2) * aw_;
  float ph  = expf(d3) * ah_;

  float x1 = pcx - 0.5f * pw;
  float y1 = pcy - 0.5f * ph;
  float x2 = pcx + 0.5f * pw;
  float y2 = pcy + 0.5f * ph;

  float imh = ish[b*2 + 0];
  float imw = ish[b*2 + 1];
  x1 = fminf(fmaxf(x1, 0.0f), imw - 1.0f);
  x2 = fminf(fmaxf(x2, 0.0f), imw - 1.0f);
  y1 = fminf(fmaxf(y1, 0.0f), imh - 1.0f);
  y2 = fminf(fmaxf(y2, 0.0f), imh - 1.0f);

  bool valid = ((x2 - x1 + 1.0f) >= 16.0f) && ((y2 - y1 + 1.0f) >= 16.0f);

  g_boxes[b][i2] = make_float4(x1, y1, x2, y2);

  unsigned int key = 0u;
  if (valid) {
    unsigned int ub = __float_as_uint(score);
    key = (ub >> 31) ? ~ub : (ub | 0x80000000u);  // monotonic flip
  }
  g_keys[b][i2] = key;
  atomicAdd(&g_h15[b][key >> HSH], 1u);           // key==0 -> bucket 0
}

// ================= k2: redundant pivot + compact =================
// grid: NB*NA*(NPOS/1024) = 216 blocks x 1024
__global__ void __launch_bounds__(1024)
k2_pivcmp(const int* __restrict__ train) {
  const int UPB = NPOS/1024;                 // 6
  int tid = threadIdx.x;
  int bid = blockIdx.x;
  int b   = bid / (NA*UPB);
  int r   = bid % (NA*UPB);
  int a   = r / UPB;
  int pos = (r % UPB) * 1024 + tid;
  int i2  = a * NPOS + pos;
  unsigned int pre = train[0] ? 12000u : 6000u;

  __shared__ unsigned int csum[1024];
  __shared__ unsigned int c32[32];
  __shared__ unsigned int c32s[33];
  __shared__ int sBest;

  // pivot = largest bucket T>=1 with suffix-count(T) >= pre
  const int CH = HSZ / 1024;   // 32 bins/thread
  unsigned int hb[CH];
  const uint4* hp = (const uint4*)&g_h15[b][tid * CH];
#pragma unroll
  for (int q = 0; q < CH/4; ++q) {
    uint4 v = hp[q];
    hb[4*q+0] = v.x; hb[4*q+1] = v.y; hb[4*q+2] = v.z; hb[4*q+3] = v.w;
  }
  unsigned int s = 0;
#pragma unroll
  for (int q = 0; q < CH; ++q) s += hb[q];
  csum[tid] = s;
  if (tid == 0) sBest = 0;
  __syncthreads();
  if (tid < 32) {
    unsigned int ss = 0;
    for (int q = 0; q < 32; ++q) ss += csum[tid*32 + q];
    c32[tid] = ss;
  }
  __syncthreads();
  if (tid == 0) {
    unsigned int run = 0; c32s[32] = 0;
    for (int c = 31; c >= 0; --c) { run += c32[c]; c32s[c] = run; }
  }
  __syncthreads();
  unsigned int run = c32s[(tid >> 5) + 1];
  for (int t2 = (tid | 31); t2 > tid; --t2) run += csum[t2];
  int loc = 0;
#pragma unroll
  for (int q = CH-1; q >= 0; --q) {
    run += hb[q];
    if (!loc && run >= pre) {
      int T = tid * CH + q;
      if (T >= 1) loc = T;
    }
  }
  if (loc) atomicMax(&sBest, loc);
  __syncthreads();
  unsigned int pivot = sBest ? ((unsigned int)sBest << HSH) : 1u;

  // compact
  unsigned int key = g_keys[b][i2];
  if (key >= pivot) {                 // pivot >= 1, key==0 auto-excluded
    int p = atomicAdd(&g_cnt[b], 1);
    if (p < CAP) {
      unsigned int iref = (unsigned int)(pos * NA + a);   // reference order
      g_cand[b][p] = ((unsigned long long)key << 32) |
                     (unsigned long long)(0xFFFFFFFFu - iref);
      g_cidx[b][p] = i2;
    }
  }
}

// ================= k3: exact rank =================
// grid: 1024 x 256; 256x256 tile sweep, k-tile in LDS (broadcast reads)
__global__ void __launch_bounds__(256) k3_rank() {
  int tid = threadIdx.x;
  __shared__ unsigned long long tl[256];
  for (int b = 0; b < NB; ++b) {
    int C = g_cnt[b]; if (C > CAP) C = CAP;
    int nt = (C + 255) >> 8;
    int tiles = nt * nt;
    for (int t = blockIdx.x; t < tiles; t += gridDim.x) {
      int jt = t / nt, kt = t - jt * nt;
      int k = kt * 256 + tid;
      tl[tid] = (k < C) ? g_cand[b][k] : 0ull;   // 0 pad: never > cj
      __syncthreads();
      int j = jt * 256 + tid;
      unsigned long long cj = (j < C) ? g_cand[b][j] : ~0ull;
      int rk = 0;
#pragma unroll 8
      for (int q = 0; q < 256; ++q) rk += (int)(tl[q] > cj);
      if (j < C && rk) atomicAdd(&g_rank[b][j], rk);
      __syncthreads();
    }
  }
}

// ================= k4: scatter + NMS | hist zero =================
// grid: 32 x 1024. blocks 0-3: NMS for image b. blocks 4-31: zero g_h15.
__global__ void __launch_bounds__(1024)
k4_nms(float* __restrict__ out, const int* __restrict__ train, int post) {
#pragma clang fp contract(off)
  int bid = blockIdx.x;
  int tid = threadIdx.x;

  if (bid >= NB) {
    // zero histogram for the next call (28 blocks, strided)
    uint4* hz = (uint4*)g_h15;
    const int total = NB*HSZ/4;
    for (int idx = (bid - NB) * 1024 + tid; idx < total; idx += 28*1024)
      hz[idx] = make_uint4(0u, 0u, 0u, 0u);
    return;
  }

  int b = bid;
  int lane = tid & 63;
  int wid  = tid >> 6;   // 16 waves
  int pre = train[0] ? 12000 : 6000;

  __shared__ float4 kbox[POSTMAX];
  __shared__ float  kar [POSTMAX];
  __shared__ float4 cbox[64];
  __shared__ float  car [64];
  __shared__ unsigned long long conf16[16][64];
  __shared__ unsigned long long sup16[16];
  __shared__ int s_nk;
  __shared__ int s_cb;

  if (tid == 0) {
    int c = g_cnt[b];
    g_cnt[b] = 0;                 // self-zero for next call (safe: same block)
    s_cb = (c > CAP) ? CAP : c;
    s_nk = 0;
  }
  __syncthreads();
  int Cb = s_cb;
  int Kb = min(pre, Cb);

  // scatter into sorted order; reset g_rank for the next call
  for (int j = tid; j < Cb; j += 1024) {
    int rkk = g_rank[b][j];
    g_rank[b][j] = 0;
    if (rkk < pre) g_sbox[b][rkk] = g_boxes[b][g_cidx[b][j]];
  }
  __syncthreads();

  // stage chunk 0
  if (wid == 15) {
    float4 bx0 = (lane < Kb) ? g_sbox[b][lane] : make_float4(0.f,0.f,-1.f,-1.f);
    cbox[lane] = bx0;
    car[lane]  = (bx0.z - bx0.x + 1.0f) * (bx0.w - bx0.y + 1.0f);
  }
  __syncthreads();

  int nk = 0;
  unsigned long long laneBitsBelow = (lane == 0) ? 0ull : (~0ull >> (64 - lane));

  for (int base = 0; base < Kb; base += 64) {
    float4 bx  = cbox[lane];
    float area = car[lane];
    bool active = (base + lane < Kb);

    // wave15: prefetch next chunk into regs (hidden under supp loop)
    float4 nxt = make_float4(0.f, 0.f, -1.f, -1.f);
    if (wid == 15) {
      int c2 = base + 64 + lane;
      if (c2 < Kb) nxt = g_sbox[b][c2];
    }

    // suppression vs kept boxes: stride-16, unrolled x4
    int supp = active ? 0 : 1;
    {
      int t = wid;
      for (; t + 48 < nk; t += 64) {
        supp |= (int)iou_gt(bx, area, kbox[t],    kar[t]);
        supp |= (int)iou_gt(bx, area, kbox[t+16], kar[t+16]);
        supp |= (int)iou_gt(bx, area, kbox[t+32], kar[t+32]);
        supp |= (int)iou_gt(bx, area, kbox[t+48], kar[t+48]);
      }
      for (; t < nk; t += 16) supp |= (int)iou_gt(bx, area, kbox[t], kar[t]);
    }
    unsigned long long sb = __ballot(supp);
    if (lane == 0) sup16[wid] = sb;

    // intra-chunk conflict bits: wave w covers j in [w*4, w*4+4)
    {
      unsigned long long confp = 0ull;
#pragma unroll
      for (int q = 0; q < 4; ++q) {
        int j = (wid << 2) + q;
        if (iou_gt(bx, area, cbox[j], car[j])) confp |= (1ull << j);
      }
      conf16[wid][lane] = confp;
    }
    __syncthreads();   // sup16/conf16 ready; cbox free to overwrite

    if (wid == 0) {
      unsigned long long conf = 0ull;
#pragma unroll
      for (int w = 0; w < 16; ++w) conf |= conf16[w][lane];
      conf &= laneBitsBelow;
      unsigned long long supAll = 0ull;
#pragma unroll
      for (int w = 0; w < 16; ++w) supAll |= sup16[w];
      unsigned long long pending = ~supAll;
      unsigned long long keptmask = 0ull;
      while (pending) {
        int i = __ffsll(pending) - 1;
        keptmask |= (1ull << i);
        unsigned long long confb = __ballot((int)((conf >> i) & 1ull));
        pending &= ~confb;
        pending &= ~(1ull << i);
      }
      int myPos = nk + __popcll(keptmask & laneBitsBelow);
      if (((keptmask >> lane) & 1ull) && myPos < post) {
        kbox[myPos] = bx;
        kar [myPos] = area;
        float* o = out + ((size_t)b * post + myPos) * 5;
        o[0] = (float)b; o[1] = bx.x; o[2] = bx.y; o[3] = bx.z; o[4] = bx.w;
      }
      if (lane == 0) s_nk = nk + __popcll(keptmask);
    } else if (wid == 15) {
      cbox[lane] = nxt;
      car[lane]  = (nxt.z - nxt.x + 1.0f) * (nxt.w - nxt.y + 1.0f);
    }
    __syncthreads();   // s_nk, kbox, new cbox ready
    nk = s_nk;
    if (nk >= post) break;
  }

  nk = min(nk, post);
  for (int rr = nk + tid; rr < post; rr += 1024) {
    float* o = out + ((size_t)b * post + rr) * 5;
    o[0] = (float)b; o[1] = 0.0f; o[2] = 0.0f; o[3] = 0.0f; o[4] = 0.0f;
  }
}

extern "C" void kernel_launch(void* const* d_in, const int* in_sizes, int n_in,
                              void* d_out, int out_size, void* d_ws, size_t ws_size,
                              hipStream_t stream) {
  (void)in_sizes; (void)n_in; (void)d_ws; (void)ws_size;
  const float* cls   = (const float*)d_in[0];
  const float* dlt   = (const float*)d_in[1];
  const float* ish   = (const float*)d_in[2];
  const int*   train = (const int*)d_in[3];
  float* out = (float*)d_out;

  int post = out_size / (NB * 5);  // 300 for TEST, 2000 for TRAIN

  k1_decode<<<NB*NA*(NPOS/256), 256, 0, stream>>>(cls, dlt, ish);
  k2_pivcmp<<<NB*NA*(NPOS/1024), 1024, 0, stream>>>(train);
  k3_rank<<<1024, 256, 0, stream>>>();
  k4_nms<<<32, 1024, 0, stream>>>(out, train, post);
}